// Round 7
// baseline (299.370 us; speedup 1.0000x reference)
//
#include <hip/hip_runtime.h>

// GCN3 round 12: revert r11 fusion (gather behind a barrier at 3 blk/CU lost
// 28us — twice-confirmed dead branch). Structure = r10 (242.8us verified),
// with the CSR build REPLACED: bucket-binning prepbin+place (12.8MB pairs
// round-trip + 3.2M LDS atomics, est ~90us) -> direct 3-kernel build:
//   k_count   : atomicAdd(cnt[dst]) per edge (+ W-pack blocks unchanged)
//   k_scanx   : block scan of cnt + atomic global cursor for base (no node-
//               order requirement on rowptr) + dis + fused xscale
//   k_scatter : p=atomicAdd(cur[dst]); csr_src[p]=src
// aggL1/gemm12/aggL2/agg1d byte-identical to r10.

typedef __attribute__((ext_vector_type(8))) short short8;   // 8 bf16 (4 VGPR)
typedef __attribute__((ext_vector_type(4))) float f32x4;    // MFMA C/D

static __device__ __forceinline__ unsigned short f2bf(float f){
  union { float f; unsigned u; } v; v.f = f;
  unsigned r = v.u + 0x7FFF + ((v.u >> 16) & 1);            // RNE
  return (unsigned short)(r >> 16);
}
static __device__ __forceinline__ float2 bf2f2(unsigned u){
  union { unsigned u; float f; } a, b;
  a.u = u << 16; b.u = u & 0xffff0000u;
  return make_float2(a.f, b.f);
}

// ---------------- k_count: per-node in-degree + W frag-pack ----------------
__global__ __launch_bounds__(256) void k_count(
    const int* __restrict__ dst, int* __restrict__ cnt, int E, int cb,
    const float* __restrict__ W1, const float* __restrict__ W2,
    unsigned short* __restrict__ Wf1, unsigned short* __restrict__ Wf2){
  int blk = blockIdx.x;
  int tid = threadIdx.x;
  if (blk < cb){
    int e0 = blk * 4096 + tid;
    #pragma unroll
    for (int i = 0; i < 16; i++){
      int e = e0 + i*256;
      if (e < E) atomicAdd(&cnt[dst[e]], 1);
    }
  } else {
    int t = (blk - cb)*256 + tid;                     // 65536 pack threads
    if (t < 32768){
      // Wf1 [16 nt][4 kt][64 lane][8 j] from W1[128][256]
      int j = t & 7, lane = (t>>3) & 63, kt = (t>>9) & 3, nt = t >> 11;
      int nn = nt*16 + (lane & 15);
      int kk = kt*32 + (lane>>4)*8 + j;
      Wf1[t] = f2bf(W1[kk*256 + nn]);
    } else {
      // Wf2 [2 h][8 kt][4 ntl][64 lane][8 j] from W2[256][128]; nt = h*4+ntl
      int o = t - 32768;
      int j = o & 7, lane = (o>>3) & 63, ntl = (o>>9) & 3, kt = (o>>11) & 7, h = o >> 14;
      int nn = (h*4 + ntl)*16 + (lane & 15);
      int kk = kt*32 + (lane>>4)*8 + j;
      Wf2[o] = f2bf(W2[kk*128 + nn]);
    }
  }
}

// ---------------- k_scanx: rowptr/cur/dis via block scan + atomic base ----------------
// rowptr ranges only need to be DISJOINT, not node-ordered, so each block
// grabs its base with one atomicAdd on a global cursor (no grid sync).
// Also fused: x -> bf16 prescale (xbs = bf16(dis*x)) for this block's nodes.
__global__ __launch_bounds__(256) void k_scanx(
    const int* __restrict__ cnt, int* __restrict__ rowptr, int* __restrict__ cur,
    float* __restrict__ dis, int* __restrict__ cursor,
    const float4* __restrict__ x, uint2* __restrict__ xbs, int n){
  __shared__ int sh[256];
  __shared__ float disl[256];
  __shared__ int sbase;
  int t = threadIdx.x;
  int b = blockIdx.x;
  int node = b*256 + t;
  int c = (node < n) ? cnt[node] : 0;
  float di = rsqrtf((float)(c + 1));                // +1 self loop
  disl[t] = di;
  sh[t] = c; __syncthreads();
  for (int off = 1; off < 256; off <<= 1){
    int xx = (t >= off) ? sh[t-off] : 0;
    __syncthreads(); sh[t] += xx; __syncthreads();
  }
  int noff = sh[t] - c;                             // exclusive scan
  if (t == 255) sbase = atomicAdd(cursor, sh[255]); // block total
  __syncthreads();
  int base = sbase;
  if (node < n){
    rowptr[node] = base + noff;
    cur[node]    = base + noff;                     // scatter cursor
    dis[node]    = di;
  }
  // fused xscale: this block's 256 nodes = float4 range [b*8192, b*8192+8192)
  const float4* xg = x + (size_t)b*8192;
  uint2* xo = xbs + (size_t)b*8192;
  int lim = n*32 - b*8192;
  for (int i = t; i < 8192 && i < lim; i += 256){
    float d = disl[i >> 5];
    float4 vv = xg[i];
    xo[i] = make_uint2((unsigned)f2bf(d*vv.x) | ((unsigned)f2bf(d*vv.y) << 16),
                       (unsigned)f2bf(d*vv.z) | ((unsigned)f2bf(d*vv.w) << 16));
  }
}

// ---------------- k_scatter: edge -> csr slot ----------------
__global__ __launch_bounds__(256) void k_scatter(
    const int* __restrict__ src, const int* __restrict__ dst,
    int* __restrict__ cur, unsigned short* __restrict__ csr_src, int E){
  int e = blockIdx.x*256 + threadIdx.x;
  if (e < E){
    int d = dst[e];
    int p = atomicAdd(&cur[d], 1);
    csr_src[p] = (unsigned short)src[e];
  }
}

// ---------------- aggregation L1: prescaled bf16 gather -> xa bf16 ----------------
__global__ void k_aggL1(const unsigned* __restrict__ xbs, unsigned* __restrict__ out,
                        const int* __restrict__ rowptr, const int* __restrict__ cnt,
                        const unsigned short* __restrict__ csr_src,
                        const float* __restrict__ dis, int n){
  int t = threadIdx.x;
  int lane = t & 63;
  int node = blockIdx.x*4 + (t >> 6);
  if (node >= n) return;
  float di = dis[node];
  float2 acc = bf2f2(xbs[(size_t)node*64 + lane]);   // self term (prescaled)
  int start = rowptr[node];
  int mm = cnt[node];
  int j = 0;
  for (; j + 15 < mm; j += 16){
    int s[16]; unsigned uv[16];
    #pragma unroll
    for (int q = 0; q < 16; q++) s[q] = csr_src[start+j+q];
    #pragma unroll
    for (int q = 0; q < 16; q++) uv[q] = xbs[(size_t)s[q]*64 + lane];
    #pragma unroll
    for (int q = 0; q < 16; q++){
      float2 u = bf2f2(uv[q]);
      acc.x += u.x; acc.y += u.y;
    }
  }
  for (; j + 3 < mm; j += 4){
    int s[4]; unsigned uv[4];
    #pragma unroll
    for (int q = 0; q < 4; q++) s[q] = csr_src[start+j+q];
    #pragma unroll
    for (int q = 0; q < 4; q++) uv[q] = xbs[(size_t)s[q]*64 + lane];
    #pragma unroll
    for (int q = 0; q < 4; q++){
      float2 u = bf2f2(uv[q]);
      acc.x += u.x; acc.y += u.y;
    }
  }
  for (; j < mm; j++){
    float2 u = bf2f2(xbs[(size_t)csr_src[start+j]*64 + lane]);
    acc.x += u.x; acc.y += u.y;
  }
  out[(size_t)node*64 + lane] =
      (unsigned)f2bf(di*acc.x) | ((unsigned)f2bf(di*acc.y) << 16);
}

// ---------------- fused GEMM1+GEMM2: xa @ W1 -> h1 (out, fp32) ; bf16(h1) @ W2 -> t2s ----------------
// 64 rows/block, 512 thr, LDS = 32KB swizzled h1 tile. Weights direct from L2.
__global__ __launch_bounds__(512) void k_gemm12(
    const unsigned short* __restrict__ Xa,
    const unsigned short* __restrict__ Wf1, const unsigned short* __restrict__ Wf2,
    const float* __restrict__ b1, const float* __restrict__ dis,
    float* __restrict__ h1, unsigned short* __restrict__ T2s, int n)
{
  __shared__ unsigned short h1l[64*256];    // 32 KB: [64 rows][256 bf16], XOR-swizzled
  int t = threadIdx.x;
  int w = t >> 6, lane = t & 63, m = lane & 15, q = lane >> 4;
  int row0 = blockIdx.x * 64;
  int stripe = w & 3;              // 16-row stripe
  int nth = w >> 2;                // col half
  int rowm = row0 + stripe*16 + m;
  int ra = (rowm < n) ? rowm : (n-1);

  // ---- GEMM1: A direct from global, B direct from L2-hot Wf1 ----
  short8 af[4];
  {
    const short8* Arow = (const short8*)(Xa + (size_t)ra*128);
    #pragma unroll
    for (int kt = 0; kt < 4; kt++) af[kt] = Arow[kt*4 + q];
  }
  f32x4 acc1[8];
  #pragma unroll
  for (int i = 0; i < 8; i++) acc1[i] = (f32x4){0.f,0.f,0.f,0.f};
  const short8* Wv1 = (const short8*)Wf1;
  #pragma unroll
  for (int nt = 0; nt < 8; nt++){
    int ntg = nth*8 + nt;
    #pragma unroll
    for (int kt = 0; kt < 4; kt++){
      short8 bfr = Wv1[(ntg*4 + kt)*64 + lane];
      acc1[nt] = __builtin_amdgcn_mfma_f32_16x16x32_bf16(af[kt], bfr, acc1[nt], 0, 0, 0);
    }
  }
  // store h1 fp32 (required output) + bf16 into swizzled LDS tile
  int rowa = row0 + stripe*16 + q*4;
  int rla  = stripe*16 + q*4;               // block-local row base
  #pragma unroll
  for (int nt = 0; nt < 8; nt++){
    int col = nth*128 + nt*16 + m;
    float b = b1[col];
    #pragma unroll
    for (int r = 0; r < 4; r++){
      int rr = rowa + r;
      float o = fmaxf(acc1[nt][r] + b, 0.0f);
      if (rr < n) h1[(size_t)rr*256 + col] = o;
      int rl = rla + r;
      unsigned byte = (unsigned)(rl*512) + (((unsigned)col*2) ^ ((unsigned)(rl & 7) << 4));
      *(unsigned short*)((char*)h1l + byte) = f2bf(o);
    }
  }
  __syncthreads();

  // ---- GEMM2: A from LDS tile (swizzled), B direct from L2-hot Wf2 ----
  short8 af2[8];
  {
    int rl = stripe*16 + m;
    #pragma unroll
    for (int kt = 0; kt < 8; kt++){
      unsigned byte = (unsigned)(rl*512) + (((unsigned)(kt*64 + q*16)) ^ ((unsigned)(rl & 7) << 4));
      af2[kt] = *(const short8*)((const char*)h1l + byte);
    }
  }
  f32x4 acc2[4];
  #pragma unroll
  for (int i = 0; i < 4; i++) acc2[i] = (f32x4){0.f,0.f,0.f,0.f};
  const short8* Wv2 = (const short8*)Wf2;
  #pragma unroll
  for (int nt = 0; nt < 4; nt++){
    #pragma unroll
    for (int kt = 0; kt < 8; kt++){
      short8 bfr = Wv2[((nth*8 + kt)*4 + nt)*64 + lane];
      acc2[nt] = __builtin_amdgcn_mfma_f32_16x16x32_bf16(af2[kt], bfr, acc2[nt], 0, 0, 0);
    }
  }
  float dsv[4];
  #pragma unroll
  for (int r = 0; r < 4; r++){
    int rr = rowa + r;
    dsv[r] = (rr < n) ? dis[rr] : 0.0f;
  }
  #pragma unroll
  for (int nt = 0; nt < 4; nt++){
    int col = nth*64 + nt*16 + m;
    #pragma unroll
    for (int r = 0; r < 4; r++){
      int rr = rowa + r;
      if (rr < n) T2s[(size_t)rr*128 + col] = f2bf(dsv[r] * acc2[nt][r]);
    }
  }
}

// ---------------- aggregation L2: prescaled gather -> h2 fp32 (+b2,relu) + us=dis*(h2.W3) ----------------
__global__ void k_aggL2(const unsigned* __restrict__ t2s, float* __restrict__ h2,
                        const int* __restrict__ rowptr, const int* __restrict__ cnt,
                        const unsigned short* __restrict__ csr_src,
                        const float* __restrict__ dis,
                        const float* __restrict__ b2, const float* __restrict__ W3,
                        float* __restrict__ u, int n){
  int t = threadIdx.x;
  int lane = t & 63;
  int node = blockIdx.x*4 + (t >> 6);
  if (node >= n) return;
  float di = dis[node];
  float2 acc = bf2f2(t2s[(size_t)node*64 + lane]);   // self term (prescaled)
  int start = rowptr[node];
  int mm = cnt[node];
  int j = 0;
  for (; j + 15 < mm; j += 16){
    int s[16]; unsigned uv[16];
    #pragma unroll
    for (int q = 0; q < 16; q++) s[q] = csr_src[start+j+q];
    #pragma unroll
    for (int q = 0; q < 16; q++) uv[q] = t2s[(size_t)s[q]*64 + lane];
    #pragma unroll
    for (int q = 0; q < 16; q++){
      float2 uu = bf2f2(uv[q]);
      acc.x += uu.x; acc.y += uu.y;
    }
  }
  for (; j + 3 < mm; j += 4){
    int s[4]; unsigned uv[4];
    #pragma unroll
    for (int q = 0; q < 4; q++) s[q] = csr_src[start+j+q];
    #pragma unroll
    for (int q = 0; q < 4; q++) uv[q] = t2s[(size_t)s[q]*64 + lane];
    #pragma unroll
    for (int q = 0; q < 4; q++){
      float2 uu = bf2f2(uv[q]);
      acc.x += uu.x; acc.y += uu.y;
    }
  }
  for (; j < mm; j++){
    float2 uu = bf2f2(t2s[(size_t)csr_src[start+j]*64 + lane]);
    acc.x += uu.x; acc.y += uu.y;
  }
  float2 b = ((const float2*)b2)[lane];
  acc.x = fmaxf(fmaf(di, acc.x, b.x), 0.0f);
  acc.y = fmaxf(fmaf(di, acc.y, b.y), 0.0f);
  ((float2*)h2)[(size_t)node*64 + lane] = acc;
  float up = fmaf(acc.x, W3[2*lane], acc.y * W3[2*lane+1]);
  #pragma unroll
  for (int off = 32; off > 0; off >>= 1) up += __shfl_down(up, off);
  if (lane == 0) u[node] = di * up;               // pre-scaled for final agg
}

// ---------------- final scalar aggregation: 16 lanes per node ----------------
__global__ void k_agg1d(const float* __restrict__ us, float* __restrict__ y,
                        const int* __restrict__ rowptr, const int* __restrict__ cnt,
                        const unsigned short* __restrict__ csr_src,
                        const float* __restrict__ dis,
                        const float* __restrict__ b3, int n){
  int t = threadIdx.x;
  int node = blockIdx.x*16 + (t >> 4);
  int sub = t & 15;
  if (node >= n) return;
  int s0 = rowptr[node];
  int m = cnt[node];
  float acc = (sub == 0) ? us[node] : 0.0f;        // self (prescaled)
  for (int j = sub; j < m; j += 16)
    acc += us[csr_src[s0 + j]];
  #pragma unroll
  for (int off = 8; off > 0; off >>= 1) acc += __shfl_xor(acc, off);
  if (sub == 0) y[node] = fmaf(dis[node], acc, b3[0]);
}

extern "C" void kernel_launch(void* const* d_in, const int* in_sizes, int n_in,
                              void* d_out, int out_size, void* d_ws, size_t ws_size,
                              hipStream_t stream){
  const float* x  = (const float*)d_in[0];
  const int*  ei  = (const int*)d_in[1];
  const float* W1 = (const float*)d_in[2];
  const float* b1 = (const float*)d_in[3];
  const float* W2 = (const float*)d_in[4];
  const float* b2 = (const float*)d_in[5];
  const float* W3 = (const float*)d_in[6];
  const float* b3 = (const float*)d_in[7];
  const int N = in_sizes[0] / 128;
  const int E = in_sizes[1] / 2;
  const int* src = ei;
  const int* dst = ei + E;
  const int NB = (N + 255) >> 8;      // 196 scan blocks

  char* p = (char*)d_ws;
  auto alloc = [&](size_t bytes)->char*{
    char* r = p; p += (bytes + 255) & ~(size_t)255; return r;
  };
  int*   rowptr  = (int*)  alloc((size_t)N*4);
  int*   cnt     = (int*)  alloc((size_t)N*4);
  int*   cur     = (int*)  alloc((size_t)N*4);
  int*   cursor  = (int*)  alloc(256);
  float* dis     = (float*)alloc((size_t)N*4);
  unsigned short* csr_src = (unsigned short*)alloc((size_t)E*2);
  unsigned* xbs  = (unsigned*)alloc((size_t)N*128*2);   // bf16 dis*x
  unsigned* xa   = (unsigned*)alloc((size_t)N*128*2);   // bf16 agg(x)
  unsigned short* t2s = (unsigned short*)alloc((size_t)N*128*2); // bf16 dis*(h1@W2)
  float* u       = (float*)alloc((size_t)N*4);          // dis*(h2@W3)
  unsigned short* wf1 = (unsigned short*)alloc(32768*2);
  unsigned short* wf2 = (unsigned short*)alloc(32768*2);

  float* y  = (float*)d_out;
  float* h1 = y + N;
  float* h2 = h1 + (size_t)N*256;

  int cb = (E + 4095)/4096;           // 196 count blocks

  hipMemsetAsync(cnt, 0, (size_t)N*4, stream);
  hipMemsetAsync(cursor, 0, 4, stream);
  k_count   <<<cb + 256, 256, 0, stream>>>(dst, cnt, E, cb, W1, W2, wf1, wf2);
  k_scanx   <<<NB, 256, 0, stream>>>(cnt, rowptr, cur, dis, cursor,
                                     (const float4*)x, (uint2*)xbs, N);
  k_scatter <<<(E + 255)/256, 256, 0, stream>>>(src, dst, cur, csr_src, E);

  int ab = (N + 3)/4;
  int rb = (N + 63)/64;
  k_aggL1   <<<ab, 256, 0, stream>>>(xbs, (unsigned*)xa, rowptr, cnt, csr_src, dis, N);
  k_gemm12  <<<rb, 512, 0, stream>>>((const unsigned short*)xa, wf1, wf2, b1, dis,
                                     h1, t2s, N);
  k_aggL2   <<<ab, 256, 0, stream>>>((const unsigned*)t2s, h2, rowptr, cnt,
                                     csr_src, dis, b2, W3, u, N);
  k_agg1d   <<<(N + 15)/16, 256, 0, stream>>>(u, y, rowptr, cnt, csr_src, dis, b3, N);
}

// Round 9
// 241.452 us; speedup vs baseline: 1.2399x; 1.2399x over previous
//
#include <hip/hip_runtime.h>

// GCN3 round 13 (resubmit; round-8 bench failed on container acquisition, not
// kernel). Revert r12's direct CSR build (random 2B scatter + global
// atomics cost +57us; binned build's bucket-local writes win). Structure =
// r10 (242.8us verified) with ONE change: aggL1/aggL2 gathers restructured
// from 1 node/wave (4B/lane) to 1 node/HALF-wave (8B/lane uint2) -> 2
// independent edge streams per wave = 2x MLP, half the load instructions.
// Same bytes, same summation order (bit-identical output).

typedef __attribute__((ext_vector_type(8))) short short8;   // 8 bf16 (4 VGPR)
typedef __attribute__((ext_vector_type(4))) float f32x4;    // MFMA C/D

static __device__ __forceinline__ unsigned short f2bf(float f){
  union { float f; unsigned u; } v; v.f = f;
  unsigned r = v.u + 0x7FFF + ((v.u >> 16) & 1);            // RNE
  return (unsigned short)(r >> 16);
}
static __device__ __forceinline__ float2 bf2f2(unsigned u){
  union { unsigned u; float f; } a, b;
  a.u = u << 16; b.u = u & 0xffff0000u;
  return make_float2(a.f, b.f);
}

// ---------------- fused: edge binning + W frag-pack ----------------
__global__ __launch_bounds__(256) void k_prepbin(
    const int* __restrict__ src, const int* __restrict__ dst,
    int* __restrict__ bcur, unsigned* __restrict__ pairs, int E, int binB,
    const float* __restrict__ W1, const float* __restrict__ W2,
    unsigned short* __restrict__ Wf1, unsigned short* __restrict__ Wf2){
  __shared__ int cl[256];
  int blk = blockIdx.x;
  int tid = threadIdx.x;
  if (blk < binB){
    int e0 = blk * 4096 + tid;
    cl[tid] = 0; __syncthreads();
    #pragma unroll
    for (int i = 0; i < 16; i++){
      int e = e0 + i*256;
      if (e < E) atomicAdd(&cl[dst[e] >> 8], 1);
    }
    __syncthreads();
    int c = cl[tid];
    int g = (c > 0) ? atomicAdd(&bcur[tid], c) : 0;   // reserve contiguous run
    cl[tid] = g;
    __syncthreads();
    #pragma unroll
    for (int i = 0; i < 16; i++){
      int e = e0 + i*256;
      if (e < E){
        int d = dst[e];
        int b = d >> 8;
        int p = atomicAdd(&cl[b], 1);
        pairs[(b << 13) + p] = (unsigned)src[e] | ((unsigned)(d & 255) << 16);
      }
    }
  } else {
    int t = (blk - binB)*256 + tid;                   // 65536 pack threads
    if (t < 32768){
      // Wf1 [16 nt][4 kt][64 lane][8 j] from W1[128][256]
      int j = t & 7, lane = (t>>3) & 63, kt = (t>>9) & 3, nt = t >> 11;
      int nn = nt*16 + (lane & 15);
      int kk = kt*32 + (lane>>4)*8 + j;
      Wf1[t] = f2bf(W1[kk*256 + nn]);
    } else {
      // Wf2 [2 h][8 kt][4 ntl][64 lane][8 j] from W2[256][128]; nt = h*4+ntl
      int o = t - 32768;
      int j = o & 7, lane = (o>>3) & 63, ntl = (o>>9) & 3, kt = (o>>11) & 7, h = o >> 14;
      int nn = (h*4 + ntl)*16 + (lane & 15);
      int kk = kt*32 + (lane>>4)*8 + j;
      Wf2[o] = f2bf(W2[kk*128 + nn]);
    }
  }
}

// one block per bucket: node histogram + scans -> rowptr/cnt/dis + csr scatter
// + fused x -> bf16 prescale (xbs = bf16(dis*x)) for this block's 256 nodes
__global__ __launch_bounds__(256) void k_place(
    const int* __restrict__ bcur, const unsigned* __restrict__ pairs,
    unsigned short* __restrict__ csr_src, int* __restrict__ rowptr,
    int* __restrict__ cnt, float* __restrict__ dis,
    const float4* __restrict__ x, uint2* __restrict__ xbs,
    int n, int nb){
  __shared__ int sh[256];
  __shared__ int ncnt[256];
  __shared__ float disl[256];
  int t = threadIdx.x;
  int b = blockIdx.x;
  int v = (t < nb) ? bcur[t] : 0;
  sh[t] = v; __syncthreads();
  for (int off = 1; off < 256; off <<= 1){
    int xx = (t >= off) ? sh[t-off] : 0;
    __syncthreads(); sh[t] += xx; __syncthreads();
  }
  int csr_base = (b == 0) ? 0 : sh[b-1];
  int cnt_b = bcur[b];
  ncnt[t] = 0; __syncthreads();
  const unsigned* P = pairs + ((size_t)b << 13);
  for (int i = t; i < cnt_b; i += 256) atomicAdd(&ncnt[P[i] >> 16], 1);
  __syncthreads();
  int c = ncnt[t];
  sh[t] = c; __syncthreads();
  for (int off = 1; off < 256; off <<= 1){
    int xx = (t >= off) ? sh[t-off] : 0;
    __syncthreads(); sh[t] += xx; __syncthreads();
  }
  int noff = sh[t] - c;
  int node = (b << 8) + t;
  float di = rsqrtf((float)(c + 1));
  disl[t] = di;
  if (node < n){
    rowptr[node] = csr_base + noff;
    cnt[node] = c;
    dis[node] = di;                               // +1 self loop
  }
  ncnt[t] = noff; __syncthreads();
  for (int i = t; i < cnt_b; i += 256){
    unsigned u = P[i];
    int p = atomicAdd(&ncnt[u >> 16], 1);
    csr_src[csr_base + p] = (unsigned short)(u & 0xffff);
  }
  // fused xscale: this block's 256 nodes = float4 range [b*8192, b*8192+8192)
  const float4* xg = x + (size_t)b*8192;
  uint2* xo = xbs + (size_t)b*8192;
  int lim = n*32 - b*8192;
  for (int i = t; i < 8192 && i < lim; i += 256){
    float d = disl[i >> 5];
    float4 vv = xg[i];
    xo[i] = make_uint2((unsigned)f2bf(d*vv.x) | ((unsigned)f2bf(d*vv.y) << 16),
                       (unsigned)f2bf(d*vv.z) | ((unsigned)f2bf(d*vv.w) << 16));
  }
}

// ---------------- aggregation L1: half-wave per node, 8B/lane ----------------
__global__ void k_aggL1(const unsigned* __restrict__ xbs, unsigned* __restrict__ out,
                        const int* __restrict__ rowptr, const int* __restrict__ cnt,
                        const unsigned short* __restrict__ csr_src,
                        const float* __restrict__ dis, int n){
  int t = threadIdx.x;
  int l = t & 31;                          // lane within half-wave
  int node = blockIdx.x*8 + (t >> 5);
  if (node >= n) return;
  float di = dis[node];
  const uint2* X = (const uint2*)xbs;
  uint2 sv = X[(size_t)node*32 + l];       // self term (prescaled)
  float2 a0 = bf2f2(sv.x), a1 = bf2f2(sv.y);
  float4 acc = make_float4(a0.x, a0.y, a1.x, a1.y);
  int start = rowptr[node];
  int mm = cnt[node];
  int j = 0;
  for (; j + 15 < mm; j += 16){
    int s[16]; uint2 uv[16];
    #pragma unroll
    for (int q = 0; q < 16; q++) s[q] = csr_src[start+j+q];
    #pragma unroll
    for (int q = 0; q < 16; q++) uv[q] = X[(size_t)s[q]*32 + l];
    #pragma unroll
    for (int q = 0; q < 16; q++){
      float2 u0 = bf2f2(uv[q].x), u1 = bf2f2(uv[q].y);
      acc.x += u0.x; acc.y += u0.y; acc.z += u1.x; acc.w += u1.y;
    }
  }
  for (; j + 3 < mm; j += 4){
    int s[4]; uint2 uv[4];
    #pragma unroll
    for (int q = 0; q < 4; q++) s[q] = csr_src[start+j+q];
    #pragma unroll
    for (int q = 0; q < 4; q++) uv[q] = X[(size_t)s[q]*32 + l];
    #pragma unroll
    for (int q = 0; q < 4; q++){
      float2 u0 = bf2f2(uv[q].x), u1 = bf2f2(uv[q].y);
      acc.x += u0.x; acc.y += u0.y; acc.z += u1.x; acc.w += u1.y;
    }
  }
  for (; j < mm; j++){
    uint2 uv = X[(size_t)csr_src[start+j]*32 + l];
    float2 u0 = bf2f2(uv.x), u1 = bf2f2(uv.y);
    acc.x += u0.x; acc.y += u0.y; acc.z += u1.x; acc.w += u1.y;
  }
  ((uint2*)out)[(size_t)node*32 + l] = make_uint2(
      (unsigned)f2bf(di*acc.x) | ((unsigned)f2bf(di*acc.y) << 16),
      (unsigned)f2bf(di*acc.z) | ((unsigned)f2bf(di*acc.w) << 16));
}

// ---------------- fused GEMM1+GEMM2: xa @ W1 -> h1 (out, fp32) ; bf16(h1) @ W2 -> t2s ----------------
// 64 rows/block, 512 thr, LDS = 32KB swizzled h1 tile. Weights direct from L2.
__global__ __launch_bounds__(512) void k_gemm12(
    const unsigned short* __restrict__ Xa,
    const unsigned short* __restrict__ Wf1, const unsigned short* __restrict__ Wf2,
    const float* __restrict__ b1, const float* __restrict__ dis,
    float* __restrict__ h1, unsigned short* __restrict__ T2s, int n)
{
  __shared__ unsigned short h1l[64*256];    // 32 KB: [64 rows][256 bf16], XOR-swizzled
  int t = threadIdx.x;
  int w = t >> 6, lane = t & 63, m = lane & 15, q = lane >> 4;
  int row0 = blockIdx.x * 64;
  int stripe = w & 3;              // 16-row stripe
  int nth = w >> 2;                // col half
  int rowm = row0 + stripe*16 + m;
  int ra = (rowm < n) ? rowm : (n-1);

  // ---- GEMM1: A direct from global, B direct from L2-hot Wf1 ----
  short8 af[4];
  {
    const short8* Arow = (const short8*)(Xa + (size_t)ra*128);
    #pragma unroll
    for (int kt = 0; kt < 4; kt++) af[kt] = Arow[kt*4 + q];
  }
  f32x4 acc1[8];
  #pragma unroll
  for (int i = 0; i < 8; i++) acc1[i] = (f32x4){0.f,0.f,0.f,0.f};
  const short8* Wv1 = (const short8*)Wf1;
  #pragma unroll
  for (int nt = 0; nt < 8; nt++){
    int ntg = nth*8 + nt;
    #pragma unroll
    for (int kt = 0; kt < 4; kt++){
      short8 bfr = Wv1[(ntg*4 + kt)*64 + lane];
      acc1[nt] = __builtin_amdgcn_mfma_f32_16x16x32_bf16(af[kt], bfr, acc1[nt], 0, 0, 0);
    }
  }
  // store h1 fp32 (required output) + bf16 into swizzled LDS tile
  int rowa = row0 + stripe*16 + q*4;
  int rla  = stripe*16 + q*4;               // block-local row base
  #pragma unroll
  for (int nt = 0; nt < 8; nt++){
    int col = nth*128 + nt*16 + m;
    float b = b1[col];
    #pragma unroll
    for (int r = 0; r < 4; r++){
      int rr = rowa + r;
      float o = fmaxf(acc1[nt][r] + b, 0.0f);
      if (rr < n) h1[(size_t)rr*256 + col] = o;
      int rl = rla + r;
      unsigned byte = (unsigned)(rl*512) + (((unsigned)col*2) ^ ((unsigned)(rl & 7) << 4));
      *(unsigned short*)((char*)h1l + byte) = f2bf(o);
    }
  }
  __syncthreads();

  // ---- GEMM2: A from LDS tile (swizzled), B direct from L2-hot Wf2 ----
  short8 af2[8];
  {
    int rl = stripe*16 + m;
    #pragma unroll
    for (int kt = 0; kt < 8; kt++){
      unsigned byte = (unsigned)(rl*512) + (((unsigned)(kt*64 + q*16)) ^ ((unsigned)(rl & 7) << 4));
      af2[kt] = *(const short8*)((const char*)h1l + byte);
    }
  }
  f32x4 acc2[4];
  #pragma unroll
  for (int i = 0; i < 4; i++) acc2[i] = (f32x4){0.f,0.f,0.f,0.f};
  const short8* Wv2 = (const short8*)Wf2;
  #pragma unroll
  for (int nt = 0; nt < 4; nt++){
    #pragma unroll
    for (int kt = 0; kt < 8; kt++){
      short8 bfr = Wv2[((nth*8 + kt)*4 + nt)*64 + lane];
      acc2[nt] = __builtin_amdgcn_mfma_f32_16x16x32_bf16(af2[kt], bfr, acc2[nt], 0, 0, 0);
    }
  }
  float dsv[4];
  #pragma unroll
  for (int r = 0; r < 4; r++){
    int rr = rowa + r;
    dsv[r] = (rr < n) ? dis[rr] : 0.0f;
  }
  #pragma unroll
  for (int nt = 0; nt < 4; nt++){
    int col = nth*64 + nt*16 + m;
    #pragma unroll
    for (int r = 0; r < 4; r++){
      int rr = rowa + r;
      if (rr < n) T2s[(size_t)rr*128 + col] = f2bf(dsv[r] * acc2[nt][r]);
    }
  }
}

// ---------------- aggregation L2: half-wave per node, 8B/lane ----------------
__global__ void k_aggL2(const unsigned* __restrict__ t2s, float* __restrict__ h2,
                        const int* __restrict__ rowptr, const int* __restrict__ cnt,
                        const unsigned short* __restrict__ csr_src,
                        const float* __restrict__ dis,
                        const float* __restrict__ b2, const float* __restrict__ W3,
                        float* __restrict__ u, int n){
  int t = threadIdx.x;
  int l = t & 31;                          // lane within half-wave
  int node = blockIdx.x*8 + (t >> 5);
  if (node >= n) return;
  float di = dis[node];
  const uint2* T = (const uint2*)t2s;
  uint2 sv = T[(size_t)node*32 + l];       // self term (prescaled)
  float2 a0 = bf2f2(sv.x), a1 = bf2f2(sv.y);
  float4 acc = make_float4(a0.x, a0.y, a1.x, a1.y);
  int start = rowptr[node];
  int mm = cnt[node];
  int j = 0;
  for (; j + 15 < mm; j += 16){
    int s[16]; uint2 uv[16];
    #pragma unroll
    for (int q = 0; q < 16; q++) s[q] = csr_src[start+j+q];
    #pragma unroll
    for (int q = 0; q < 16; q++) uv[q] = T[(size_t)s[q]*32 + l];
    #pragma unroll
    for (int q = 0; q < 16; q++){
      float2 u0 = bf2f2(uv[q].x), u1 = bf2f2(uv[q].y);
      acc.x += u0.x; acc.y += u0.y; acc.z += u1.x; acc.w += u1.y;
    }
  }
  for (; j + 3 < mm; j += 4){
    int s[4]; uint2 uv[4];
    #pragma unroll
    for (int q = 0; q < 4; q++) s[q] = csr_src[start+j+q];
    #pragma unroll
    for (int q = 0; q < 4; q++) uv[q] = T[(size_t)s[q]*32 + l];
    #pragma unroll
    for (int q = 0; q < 4; q++){
      float2 u0 = bf2f2(uv[q].x), u1 = bf2f2(uv[q].y);
      acc.x += u0.x; acc.y += u0.y; acc.z += u1.x; acc.w += u1.y;
    }
  }
  for (; j < mm; j++){
    uint2 uv = T[(size_t)csr_src[start+j]*32 + l];
    float2 u0 = bf2f2(uv.x), u1 = bf2f2(uv.y);
    acc.x += u0.x; acc.y += u0.y; acc.z += u1.x; acc.w += u1.y;
  }
  float4 b = ((const float4*)b2)[l];
  acc.x = fmaxf(fmaf(di, acc.x, b.x), 0.0f);
  acc.y = fmaxf(fmaf(di, acc.y, b.y), 0.0f);
  acc.z = fmaxf(fmaf(di, acc.z, b.z), 0.0f);
  acc.w = fmaxf(fmaf(di, acc.w, b.w), 0.0f);
  ((float4*)h2)[(size_t)node*32 + l] = acc;
  float4 wv = ((const float4*)W3)[l];
  float up = acc.x*wv.x + acc.y*wv.y + acc.z*wv.z + acc.w*wv.w;
  #pragma unroll
  for (int off = 16; off > 0; off >>= 1) up += __shfl_down(up, off, 32);
  if (l == 0) u[node] = di * up;           // pre-scaled for final agg
}

// ---------------- final scalar aggregation: 16 lanes per node ----------------
__global__ void k_agg1d(const float* __restrict__ us, float* __restrict__ y,
                        const int* __restrict__ rowptr, const int* __restrict__ cnt,
                        const unsigned short* __restrict__ csr_src,
                        const float* __restrict__ dis,
                        const float* __restrict__ b3, int n){
  int t = threadIdx.x;
  int node = blockIdx.x*16 + (t >> 4);
  int sub = t & 15;
  if (node >= n) return;
  int s0 = rowptr[node];
  int m = cnt[node];
  float acc = (sub == 0) ? us[node] : 0.0f;        // self (prescaled)
  for (int j = sub; j < m; j += 16)
    acc += us[csr_src[s0 + j]];
  #pragma unroll
  for (int off = 8; off > 0; off >>= 1) acc += __shfl_xor(acc, off);
  if (sub == 0) y[node] = fmaf(dis[node], acc, b3[0]);
}

extern "C" void kernel_launch(void* const* d_in, const int* in_sizes, int n_in,
                              void* d_out, int out_size, void* d_ws, size_t ws_size,
                              hipStream_t stream){
  const float* x  = (const float*)d_in[0];
  const int*  ei  = (const int*)d_in[1];
  const float* W1 = (const float*)d_in[2];
  const float* b1 = (const float*)d_in[3];
  const float* W2 = (const float*)d_in[4];
  const float* b2 = (const float*)d_in[5];
  const float* W3 = (const float*)d_in[6];
  const float* b3 = (const float*)d_in[7];
  const int N = in_sizes[0] / 128;
  const int E = in_sizes[1] / 2;
  const int* src = ei;
  const int* dst = ei + E;
  const int NB = (N + 255) >> 8;      // 196 buckets

  char* p = (char*)d_ws;
  auto alloc = [&](size_t bytes)->char*{
    char* r = p; p += (bytes + 255) & ~(size_t)255; return r;
  };
  int*   bcur    = (int*)  alloc(256*4);
  int*   rowptr  = (int*)  alloc((size_t)N*4);
  int*   cnt     = (int*)  alloc((size_t)N*4);
  float* dis     = (float*)alloc((size_t)N*4);
  unsigned* pairs = (unsigned*)alloc((size_t)NB*8192*4);
  unsigned short* csr_src = (unsigned short*)alloc((size_t)E*2);
  unsigned* xbs  = (unsigned*)alloc((size_t)N*128*2);   // bf16 dis*x
  unsigned* xa   = (unsigned*)alloc((size_t)N*128*2);   // bf16 agg(x)
  unsigned short* t2s = (unsigned short*)alloc((size_t)N*128*2); // bf16 dis*(h1@W2)
  float* u       = (float*)alloc((size_t)N*4);          // dis*(h2@W3)
  unsigned short* wf1 = (unsigned short*)alloc(32768*2);
  unsigned short* wf2 = (unsigned short*)alloc(32768*2);

  float* y  = (float*)d_out;
  float* h1 = y + N;
  float* h2 = h1 + (size_t)N*256;

  int bb = (E + 4095)/4096;           // 196 bin blocks

  hipMemsetAsync(bcur, 0, 256*4, stream);
  k_prepbin <<<bb + 256, 256, 0, stream>>>(
      src, dst, bcur, pairs, E, bb, W1, W2, wf1, wf2);
  k_place   <<<NB, 256, 0, stream>>>(bcur, pairs, csr_src, rowptr, cnt, dis,
                                     (const float4*)x, (uint2*)xbs, N, NB);

  int ab = (N + 7)/8;
  int rb = (N + 63)/64;
  k_aggL1   <<<ab, 256, 0, stream>>>(xbs, (unsigned*)xa, rowptr, cnt, csr_src, dis, N);
  k_gemm12  <<<rb, 512, 0, stream>>>((const unsigned short*)xa, wf1, wf2, b1, dis,
                                     h1, t2s, N);
  k_aggL2   <<<ab, 256, 0, stream>>>((const unsigned*)t2s, h2, rowptr, cnt,
                                     csr_src, dis, b2, W3, u, N);
  k_agg1d   <<<(N + 15)/16, 256, 0, stream>>>(u, y, rowptr, cnt, csr_src, dis, b3, N);
}